// Round 2
// baseline (23100.180 us; speedup 1.0000x reference)
//
#include <hip/hip_runtime.h>
#include <hip/hip_bf16.h>
#include <math.h>

#define BATCH 64
#define TLEN  512
#define DIN   300
#define RDIM  2048

#define NBLK 256
#define NTHR 512

typedef __attribute__((ext_vector_type(4))) float f32x4;
typedef __attribute__((ext_vector_type(8))) short bf16x8;

__device__ __forceinline__ unsigned short f32_bf16_rne(float f) {
    unsigned int u = __float_as_uint(f);
    u += 0x7fffu + ((u >> 16) & 1u);
    return (unsigned short)(u >> 16);
}
__device__ __forceinline__ float bf16_f32(unsigned short h) {
    return __uint_as_float(((unsigned int)h) << 16);
}

// ---------------- W -> bf16 hi/lo split (one-time) ----------------
__global__ __launch_bounds__(256) void k_wsplit(const float* __restrict__ W,
                                                unsigned short* __restrict__ Whi,
                                                unsigned short* __restrict__ Wlo) {
    int i = (blockIdx.x * 256 + threadIdx.x) * 4;
    f32x4 w = *(const f32x4*)(W + i);
    ushort4 hi, lo;
    unsigned short h0 = f32_bf16_rne(w[0]); hi.x = h0; lo.x = f32_bf16_rne(w[0] - bf16_f32(h0));
    unsigned short h1 = f32_bf16_rne(w[1]); hi.y = h1; lo.y = f32_bf16_rne(w[1] - bf16_f32(h1));
    unsigned short h2 = f32_bf16_rne(w[2]); hi.z = h2; lo.z = f32_bf16_rne(w[2] - bf16_f32(h2));
    unsigned short h3 = f32_bf16_rne(w[3]); hi.w = h3; lo.w = f32_bf16_rne(w[3] - bf16_f32(h3));
    *(ushort4*)(Whi + i) = hi;
    *(ushort4*)(Wlo + i) = lo;
}

// ---------------- Kernel A: U = x @ Win^T (fp32), writes into out ----------------
#define A_BM 128
#define A_BN 64
#define A_BK 20
#define XS_STRIDE 132
#define WS_STRIDE 68

__global__ __launch_bounds__(256) void k_proj(const float* __restrict__ x,
                                              const float* __restrict__ Win,
                                              float* __restrict__ hseq,
                                              unsigned short* h0hi,
                                              unsigned short* h0lo,
                                              int do_split) {
    __shared__ __align__(16) float xs[A_BK * XS_STRIDE];
    __shared__ __align__(16) float wsh[A_BK * WS_STRIDE];
    const int tid = threadIdx.x;
    const int tx = tid & 15;
    const int ty = tid >> 4;
    const int m0 = blockIdx.y * A_BM;
    const int n0 = blockIdx.x * A_BN;

    float acc[8][4];
#pragma unroll
    for (int i = 0; i < 8; ++i)
#pragma unroll
        for (int j = 0; j < 4; ++j) acc[i][j] = 0.0f;

    for (int k0 = 0; k0 < DIN; k0 += A_BK) {
#pragma unroll
        for (int s = 0; s < (A_BM * A_BK) / 256; ++s) {
            int idx = tid + s * 256;
            int row = idx / A_BK, col = idx - row * A_BK;
            xs[col * XS_STRIDE + row] = x[(m0 + row) * DIN + k0 + col];
        }
#pragma unroll
        for (int s = 0; s < (A_BN * A_BK) / 256; ++s) {
            int idx = tid + s * 256;
            int row = idx / A_BK, col = idx - row * A_BK;
            wsh[col * WS_STRIDE + row] = Win[(n0 + row) * DIN + k0 + col];
        }
        __syncthreads();
#pragma unroll
        for (int kk = 0; kk < A_BK; ++kk) {
            f32x4 xv0 = *(const f32x4*)&xs[kk * XS_STRIDE + ty * 8];
            f32x4 xv1 = *(const f32x4*)&xs[kk * XS_STRIDE + ty * 8 + 4];
            f32x4 wv  = *(const f32x4*)&wsh[kk * WS_STRIDE + tx * 4];
#pragma unroll
            for (int i = 0; i < 4; ++i)
#pragma unroll
                for (int j = 0; j < 4; ++j) acc[i][j] += xv0[i] * wv[j];
#pragma unroll
            for (int i = 0; i < 4; ++i)
#pragma unroll
                for (int j = 0; j < 4; ++j) acc[4 + i][j] += xv1[i] * wv[j];
        }
        __syncthreads();
    }

#pragma unroll
    for (int i = 0; i < 8; ++i) {
        int m = m0 + ty * 8 + i;
        int t = m & (TLEN - 1);
        int b = m >> 9;
        int r0 = n0 + tx * 4;
        f32x4 v;
#pragma unroll
        for (int j = 0; j < 4; ++j) v[j] = acc[i][j];
        if (t == 0) {
#pragma unroll
            for (int j = 0; j < 4; ++j) v[j] = tanhf(v[j]);
            if (do_split) {
#pragma unroll
                for (int j = 0; j < 4; ++j) {
                    unsigned short hi = f32_bf16_rne(v[j]);
                    h0hi[b * RDIM + r0 + j] = hi;
                    h0lo[b * RDIM + r0 + j] = f32_bf16_rne(v[j] - bf16_f32(hi));
                }
            }
        }
        *(f32x4*)(hseq + ((size_t)t * BATCH + b) * RDIM + r0) = v;
    }
}

// ---------------- device-scope grid barrier ----------------
__device__ __forceinline__ void grid_barrier(unsigned int* bar) {
    __syncthreads();
    if (threadIdx.x == 0) {
        __threadfence();  // release: flush this XCD's dirty lines to coherence point
        unsigned int g = __hip_atomic_load(&bar[1], __ATOMIC_RELAXED, __HIP_MEMORY_SCOPE_AGENT);
        unsigned int old = __hip_atomic_fetch_add(&bar[0], 1u, __ATOMIC_ACQ_REL, __HIP_MEMORY_SCOPE_AGENT);
        if (old == NBLK - 1) {
            __hip_atomic_store(&bar[0], 0u, __ATOMIC_RELAXED, __HIP_MEMORY_SCOPE_AGENT);
            __hip_atomic_store(&bar[1], g + 1u, __ATOMIC_RELEASE, __HIP_MEMORY_SCOPE_AGENT);
        } else {
            int spins = 0;
            while (__hip_atomic_load(&bar[1], __ATOMIC_ACQUIRE, __HIP_MEMORY_SCOPE_AGENT) == g) {
                __builtin_amdgcn_s_sleep(2);
                if (++spins > (1 << 20)) break;  // hang failsafe (fails loudly, not silently)
            }
        }
        __threadfence();  // acquire: invalidate stale L1/L2
    }
    __syncthreads();
}

// ---------------- persistent step engine: t = 1..511 ----------------
// 256 blocks x 512 threads. Block = [32m x 16n] tile (mh = blk>>7, ns = blk&127).
// 8 waves K-split (256 each); W slice held in registers (hi+lo = 64 VGPRs/wave).
__global__ __launch_bounds__(NTHR, 2) void k_persist(
    float* hseq,
    const unsigned short* __restrict__ Whi,
    const unsigned short* __restrict__ Wlo,
    unsigned short* hs_hi0, unsigned short* hs_lo0,
    unsigned short* hs_hi1, unsigned short* hs_lo1,
    unsigned int* bar) {
    __shared__ float part[16 * 256];  // [w*2+mt][row*16+col]
    const int tid = threadIdx.x;
    const int w = tid >> 6;
    const int lane = tid & 63;
    const int l15 = lane & 15;
    const int q = lane >> 4;
    const int b = blockIdx.x;
    const int ns = b & 127;
    const int mh = b >> 7;

    const int brow = ns * 16 + l15;
    const int kb = w * 256 + q * 8;

    // preload this wave's W slice into registers (stays for all 511 steps)
    bf16x8 Bh[8], Bl[8];
#pragma unroll
    for (int i = 0; i < 8; ++i) {
        Bh[i] = *(const bf16x8*)(Whi + (size_t)brow * RDIM + kb + i * 32);
        Bl[i] = *(const bf16x8*)(Wlo + (size_t)brow * RDIM + kb + i * 32);
    }

    const int arow0 = mh * 32 + l15;
    const int arow1 = mh * 32 + 16 + l15;

    // epilogue element for this thread
    const int emt = tid >> 8;
    const int erow = (tid >> 4) & 15;
    const int ecol = tid & 15;
    const int earow = mh * 32 + emt * 16 + erow;
    const size_t eo = (size_t)earow * RDIM + ns * 16 + ecol;

    unsigned short* hhi[2] = { hs_hi0, hs_hi1 };
    unsigned short* hlo[2] = { hs_lo0, hs_lo1 };

    for (int t = 1; t < TLEN; ++t) {
        float* outt = hseq + (size_t)t * BATCH * RDIM;
        const float* outp = hseq + (size_t)(t - 1) * BATCH * RDIM;
        // prefetch epilogue operands early (independent of this step's GEMM)
        float u = outt[eo];
        float hp = outp[eo];

        const unsigned short* phi = hhi[(t - 1) & 1];
        const unsigned short* plo = hlo[(t - 1) & 1];
        const unsigned short* a0h = phi + (size_t)arow0 * RDIM + kb;
        const unsigned short* a0l = plo + (size_t)arow0 * RDIM + kb;
        const unsigned short* a1h = phi + (size_t)arow1 * RDIM + kb;
        const unsigned short* a1l = plo + (size_t)arow1 * RDIM + kb;

        f32x4 acc0 = { 0.f, 0.f, 0.f, 0.f };
        f32x4 acc1 = { 0.f, 0.f, 0.f, 0.f };
#pragma unroll
        for (int i = 0; i < 8; ++i) {
            bf16x8 ah0 = *(const bf16x8*)(a0h + i * 32);
            bf16x8 al0 = *(const bf16x8*)(a0l + i * 32);
            bf16x8 ah1 = *(const bf16x8*)(a1h + i * 32);
            bf16x8 al1 = *(const bf16x8*)(a1l + i * 32);
            acc0 = __builtin_amdgcn_mfma_f32_16x16x32_bf16(ah0, Bh[i], acc0, 0, 0, 0);
            acc1 = __builtin_amdgcn_mfma_f32_16x16x32_bf16(ah1, Bh[i], acc1, 0, 0, 0);
            acc0 = __builtin_amdgcn_mfma_f32_16x16x32_bf16(al0, Bh[i], acc0, 0, 0, 0);
            acc1 = __builtin_amdgcn_mfma_f32_16x16x32_bf16(al1, Bh[i], acc1, 0, 0, 0);
            acc0 = __builtin_amdgcn_mfma_f32_16x16x32_bf16(ah0, Bl[i], acc0, 0, 0, 0);
            acc1 = __builtin_amdgcn_mfma_f32_16x16x32_bf16(ah1, Bl[i], acc1, 0, 0, 0);
        }

        // partials -> LDS  (C layout: col = lane&15, row = q*4 + v)
#pragma unroll
        for (int v = 0; v < 4; ++v) {
            part[(w * 2 + 0) * 256 + (q * 4 + v) * 16 + l15] = acc0[v];
            part[(w * 2 + 1) * 256 + (q * 4 + v) * 16 + l15] = acc1[v];
        }
        __syncthreads();

        // reduce 8 K-partials + fused epilogue (one element per thread)
        float s = 0.f;
#pragma unroll
        for (int ww = 0; ww < 8; ++ww) s += part[(ww * 2 + emt) * 256 + (tid & 255)];
        float raw = tanhf(s + u);
        float h = (t >= 2) ? 0.5f * raw + 0.5f * hp : raw;
        outt[eo] = h;
        unsigned short hi16 = f32_bf16_rne(h);
        hhi[t & 1][eo] = hi16;
        hlo[t & 1][eo] = f32_bf16_rne(h - bf16_f32(hi16));

        grid_barrier(bar);  // also protects LDS `part` reuse next step
    }
}

// ---------------- fallback per-step kernel (ws too small; fp32 path) ----------------
__global__ __launch_bounds__(256) void k_step_f32(float* hseq,
                                                  const float* __restrict__ Wf,
                                                  int t) {
    const int lane = threadIdx.x & 63;
    const int wave = threadIdx.x >> 6;
    const int l15 = lane & 15;
    const int q = lane >> 4;
    const int n0 = blockIdx.x * 16;
    const int m0 = wave * 16;

    const int arow = m0 + l15;
    const int brow = n0 + l15;
    const int kbase = q * 8;

    f32x4 acc = { 0.f, 0.f, 0.f, 0.f };
    const float* hprev_f = hseq + (size_t)(t - 1) * BATCH * RDIM;
    const float* af = hprev_f + arow * RDIM + kbase;
    const float* bfp = Wf + brow * RDIM + kbase;
#pragma unroll 2
    for (int k = 0; k < RDIM; k += 32) {
        f32x4 a0 = *(const f32x4*)(af + k);
        f32x4 a1 = *(const f32x4*)(af + k + 4);
        f32x4 b0 = *(const f32x4*)(bfp + k);
        f32x4 b1 = *(const f32x4*)(bfp + k + 4);
        bf16x8 ahi, alo, bhi, blo;
#pragma unroll
        for (int j = 0; j < 4; ++j) {
            unsigned short h;
            h = f32_bf16_rne(a0[j]); ahi[j] = (short)h; alo[j] = (short)f32_bf16_rne(a0[j] - bf16_f32(h));
            h = f32_bf16_rne(a1[j]); ahi[4 + j] = (short)h; alo[4 + j] = (short)f32_bf16_rne(a1[j] - bf16_f32(h));
            h = f32_bf16_rne(b0[j]); bhi[j] = (short)h; blo[j] = (short)f32_bf16_rne(b0[j] - bf16_f32(h));
            h = f32_bf16_rne(b1[j]); bhi[4 + j] = (short)h; blo[4 + j] = (short)f32_bf16_rne(b1[j] - bf16_f32(h));
        }
        acc = __builtin_amdgcn_mfma_f32_16x16x32_bf16(ahi, bhi, acc, 0, 0, 0);
        acc = __builtin_amdgcn_mfma_f32_16x16x32_bf16(alo, bhi, acc, 0, 0, 0);
        acc = __builtin_amdgcn_mfma_f32_16x16x32_bf16(ahi, blo, acc, 0, 0, 0);
    }

    float* outt = hseq + (size_t)t * BATCH * RDIM;
#pragma unroll
    for (int v = 0; v < 4; ++v) {
        int bb = m0 + q * 4 + v;
        size_t o = (size_t)bb * RDIM + brow;
        float raw = tanhf(acc[v] + outt[o]);
        float hp = hprev_f[o];
        float h = (t >= 2) ? 0.5f * raw + 0.5f * hp : raw;
        outt[o] = h;
    }
}

extern "C" void kernel_launch(void* const* d_in, const int* in_sizes, int n_in,
                              void* d_out, int out_size, void* d_ws, size_t ws_size,
                              hipStream_t stream) {
    const float* x   = (const float*)d_in[0];
    const float* Win = (const float*)d_in[1];
    const float* W   = (const float*)d_in[2];
    float* out = (float*)d_out;

    const size_t wElems = (size_t)RDIM * RDIM;
    const size_t hElems = (size_t)BATCH * RDIM;
    // layout: Whi | Wlo | hhi0 | hlo0 | hhi1 | hlo1 | barrier(128B)
    const size_t need = wElems * 2 * sizeof(unsigned short) +
                        hElems * 4 * sizeof(unsigned short) + 128;
    const bool split = ws_size >= need;

    unsigned short* Whi = (unsigned short*)d_ws;
    unsigned short* Wlo = Whi + wElems;
    unsigned short* hb  = Wlo + wElems;
    unsigned short* hh0 = hb;
    unsigned short* hl0 = hb + hElems;
    unsigned short* hh1 = hb + 2 * hElems;
    unsigned short* hl1 = hb + 3 * hElems;
    unsigned int* bar = (unsigned int*)(hb + 4 * hElems);

    if (split) {
        hipMemsetAsync((void*)bar, 0, 128, stream);
        k_wsplit<<<(int)(wElems / 1024), 256, 0, stream>>>(W, Whi, Wlo);
    }

    dim3 gA(RDIM / A_BN, (BATCH * TLEN) / A_BM);
    k_proj<<<gA, 256, 0, stream>>>(x, Win, out, split ? hh0 : nullptr,
                                   split ? hl0 : nullptr, split ? 1 : 0);

    if (split) {
        k_persist<<<NBLK, NTHR, 0, stream>>>(out, Whi, Wlo, hh0, hl0, hh1, hl1, bar);
    } else {
        for (int t = 1; t < TLEN; ++t) {
            k_step_f32<<<RDIM / 16, 256, 0, stream>>>(out, W, t);
        }
    }
}